// Round 7
// baseline (504.782 us; speedup 1.0000x reference)
//
#include <hip/hip_runtime.h>

#define BDIM 8192
#define KTOP 3
#define TAU 0.1f
#define MARGIN_MIN 0.1f
#define MARGIN_MAX 0.3f
#define NEG_FILL -50.0f

// branchless insert of v into descending top-3 (a >= b >= c)
__device__ __forceinline__ void ins3(float v, float& a, float& b, float& c) {
    const float mav = fminf(a, v);
    const float mbv = fminf(b, mav);
    a = fmaxf(a, v);
    b = fmaxf(b, mav);
    c = fmaxf(c, mbv);
}

__global__ __launch_bounds__(256) void row_topk_loss_fused_kernel(
        const float* __restrict__ in, const int* __restrict__ tg,
        float* __restrict__ rowloss, unsigned int* __restrict__ ticket,
        float* __restrict__ out) {
    const int row = blockIdx.x;
    const int t   = threadIdx.x;

    const float4* inr = reinterpret_cast<const float4*>(in + (size_t)row * BDIM);
    const int4*   tgr = reinterpret_cast<const int4*>(tg + (size_t)row * BDIM);

    // batch all loads first: 8 float4 + 8 int4 in flight per thread
    float4 v[8];
    int4   m[8];
    #pragma unroll
    for (int k = 0; k < 8; ++k) v[k] = inr[t + k * 256];
    #pragma unroll
    for (int k = 0; k < 8; ++k) m[k] = tgr[t + k * 256];

    float a = NEG_FILL, b = NEG_FILL, c = NEG_FILL;
    #pragma unroll
    for (int k = 0; k < 8; ++k) {
        ins3((m[k].x == 0) ? v[k].x : NEG_FILL, a, b, c);
        ins3((m[k].y == 0) ? v[k].y : NEG_FILL, a, b, c);
        ins3((m[k].z == 0) ? v[k].z : NEG_FILL, a, b, c);
        ins3((m[k].w == 0) ? v[k].w : NEG_FILL, a, b, c);
    }

    // 64-lane wave top-3 merge (branchless -> no divergence)
    #pragma unroll
    for (int off = 32; off > 0; off >>= 1) {
        const float oa = __shfl_down(a, off, 64);
        const float ob = __shfl_down(b, off, 64);
        const float oc = __shfl_down(c, off, 64);
        ins3(oa, a, b, c);
        ins3(ob, a, b, c);
        ins3(oc, a, b, c);
    }

    __shared__ float sa[4], sb[4], sc[4];
    __shared__ float sdiag;
    __shared__ unsigned int is_last;
    __shared__ float s[256];
    if ((t & 63) == 0) {
        const int w = t >> 6;
        sa[w] = a; sb[w] = b; sc[w] = c;
    }
    if (t == 0) sdiag = in[(size_t)row * BDIM + row];
    __syncthreads();

    if (t == 0) {
        float A = sa[0], Bv = sb[0], C = sc[0];
        #pragma unroll
        for (int w = 1; w < 4; ++w) {
            ins3(sa[w], A, Bv, C);
            ins3(sb[w], A, Bv, C);
            ins3(sc[w], A, Bv, C);
        }
        const float sp = sdiag;
        float sn[KTOP] = {A, Bv, C};
        float loss[KTOP], msk[KTOP];
        float mx = -1e30f;
        #pragma unroll
        for (int k = 0; k < KTOP; ++k) {
            float dm = fabsf(sp - sn[k]);
            dm = fminf(fmaxf(dm, MARGIN_MIN), MARGIN_MAX);
            const float l = fmaxf(0.0f, sn[k] - sp + dm);
            loss[k] = l;
            msk[k]  = (l == 0.0f) ? NEG_FILL : sn[k];
            mx = fmaxf(mx, msk[k]);
        }
        float se = 0.0f, num = 0.0f;
        #pragma unroll
        for (int k = 0; k < KTOP; ++k) {
            const float e = __expf((msk[k] - mx) * (1.0f / TAU));
            se  += e;
            num += loss[k] * e;
        }
        rowloss[row] = num / se;

        // release: make rowloss[row] visible device-wide, then take a ticket
        __threadfence();
        const unsigned int old = atomicAdd(ticket, 1u);
        is_last = (old == (unsigned int)(BDIM - 1)) ? 1u : 0u;
    }
    __syncthreads();

    // last-arriving block performs the deterministic fixed-order mean
    if (is_last) {
        __threadfence();  // acquire side
        float sum = 0.0f;
        #pragma unroll
        for (int k = 0; k < 32; ++k) {
            // agent-scope load: bypass stale L1/L2 (cross-XCD non-coherence)
            sum += __hip_atomic_load(&rowloss[t + k * 256],
                                     __ATOMIC_RELAXED, __HIP_MEMORY_SCOPE_AGENT);
        }
        s[t] = sum;
        __syncthreads();
        for (int off = 128; off > 0; off >>= 1) {
            if (t < off) s[t] += s[t + off];
            __syncthreads();
        }
        if (t == 0) out[0] = s[0] / (float)(BDIM * KTOP);
    }
}

extern "C" void kernel_launch(void* const* d_in, const int* in_sizes, int n_in,
                              void* d_out, int out_size, void* d_ws, size_t ws_size,
                              hipStream_t stream) {
    const float* in = (const float*)d_in[0];
    const int*   tg = (const int*)d_in[1];
    float* rowloss = (float*)d_ws;                       // 8192 floats, all rewritten each call
    unsigned int* ticket = (unsigned int*)((char*)d_ws + BDIM * sizeof(float));
    float* out = (float*)d_out;

    // reset the ticket each call (graph-capturable async memset; deterministic)
    hipMemsetAsync(ticket, 0, sizeof(unsigned int), stream);
    row_topk_loss_fused_kernel<<<BDIM, 256, 0, stream>>>(in, tg, rowloss, ticket, out);
}

// Round 8
// 84.482 us; speedup vs baseline: 5.9750x; 5.9750x over previous
//
#include <hip/hip_runtime.h>

#define BDIM 8192
#define KTOP 3
#define TAU 0.1f
#define MARGIN_MIN 0.1f
#define MARGIN_MAX 0.3f
#define NEG_FILL -50.0f

typedef float f4v __attribute__((ext_vector_type(4)));
typedef int   i4v __attribute__((ext_vector_type(4)));

// branchless insert of v into descending top-3 (a >= b >= c)
__device__ __forceinline__ void ins3(float v, float& a, float& b, float& c) {
    const float mav = fminf(a, v);
    const float mbv = fminf(b, mav);
    a = fmaxf(a, v);
    b = fmaxf(b, mav);
    c = fmaxf(c, mbv);
}

__global__ __launch_bounds__(256) void row_topk_loss_kernel(
        const float* __restrict__ in, const int* __restrict__ tg,
        float* __restrict__ rowloss) {
    const int row = blockIdx.x;
    const int t   = threadIdx.x;

    const f4v* inr = reinterpret_cast<const f4v*>(in + (size_t)row * BDIM);
    const i4v* tgr = reinterpret_cast<const i4v*>(tg + (size_t)row * BDIM);

    // batch all loads first: 8 float4 + 8 int4 in flight per thread.
    // nontemporal: pure stream, zero reuse -> don't pollute L2/L3.
    f4v v[8];
    i4v m[8];
    #pragma unroll
    for (int k = 0; k < 8; ++k) v[k] = __builtin_nontemporal_load(&inr[t + k * 256]);
    #pragma unroll
    for (int k = 0; k < 8; ++k) m[k] = __builtin_nontemporal_load(&tgr[t + k * 256]);

    float a = NEG_FILL, b = NEG_FILL, c = NEG_FILL;
    #pragma unroll
    for (int k = 0; k < 8; ++k) {
        ins3((m[k].x == 0) ? v[k].x : NEG_FILL, a, b, c);
        ins3((m[k].y == 0) ? v[k].y : NEG_FILL, a, b, c);
        ins3((m[k].z == 0) ? v[k].z : NEG_FILL, a, b, c);
        ins3((m[k].w == 0) ? v[k].w : NEG_FILL, a, b, c);
    }

    // 64-lane wave top-3 merge (branchless -> no divergence)
    #pragma unroll
    for (int off = 32; off > 0; off >>= 1) {
        const float oa = __shfl_down(a, off, 64);
        const float ob = __shfl_down(b, off, 64);
        const float oc = __shfl_down(c, off, 64);
        ins3(oa, a, b, c);
        ins3(ob, a, b, c);
        ins3(oc, a, b, c);
    }

    __shared__ float sa[4], sb[4], sc[4];
    __shared__ float sdiag;
    if ((t & 63) == 0) {
        const int w = t >> 6;
        sa[w] = a; sb[w] = b; sc[w] = c;
    }
    if (t == 0) sdiag = in[(size_t)row * BDIM + row];
    __syncthreads();

    if (t == 0) {
        float A = sa[0], Bv = sb[0], C = sc[0];
        #pragma unroll
        for (int w = 1; w < 4; ++w) {
            ins3(sa[w], A, Bv, C);
            ins3(sb[w], A, Bv, C);
            ins3(sc[w], A, Bv, C);
        }
        const float sp = sdiag;
        float sn[KTOP] = {A, Bv, C};
        float loss[KTOP], msk[KTOP];
        float mx = -1e30f;
        #pragma unroll
        for (int k = 0; k < KTOP; ++k) {
            float dm = fabsf(sp - sn[k]);
            dm = fminf(fmaxf(dm, MARGIN_MIN), MARGIN_MAX);
            const float l = fmaxf(0.0f, sn[k] - sp + dm);
            loss[k] = l;
            msk[k]  = (l == 0.0f) ? NEG_FILL : sn[k];
            mx = fmaxf(mx, msk[k]);
        }
        float se = 0.0f, num = 0.0f;
        #pragma unroll
        for (int k = 0; k < KTOP; ++k) {
            const float e = __expf((msk[k] - mx) * (1.0f / TAU));
            se  += e;
            num += loss[k] * e;
        }
        rowloss[row] = num / se;
    }
}

// deterministic fixed-order sum of the 8192 per-row losses -> scalar mean
__global__ __launch_bounds__(256) void reduce_kernel(
        const float* __restrict__ rowloss, float* __restrict__ out) {
    __shared__ float s[256];
    const int t = threadIdx.x;
    float sum = 0.0f;
    #pragma unroll
    for (int k = 0; k < 32; ++k) sum += rowloss[t + k * 256];
    s[t] = sum;
    __syncthreads();
    for (int off = 128; off > 0; off >>= 1) {
        if (t < off) s[t] += s[t + off];
        __syncthreads();
    }
    if (t == 0) out[0] = s[0] / (float)(BDIM * KTOP);
}

extern "C" void kernel_launch(void* const* d_in, const int* in_sizes, int n_in,
                              void* d_out, int out_size, void* d_ws, size_t ws_size,
                              hipStream_t stream) {
    const float* in = (const float*)d_in[0];
    const int*   tg = (const int*)d_in[1];
    float* rowloss = (float*)d_ws;   // 8192 floats; every slot rewritten each call
    float* out = (float*)d_out;

    row_topk_loss_kernel<<<BDIM, 256, 0, stream>>>(in, tg, rowloss);
    reduce_kernel<<<1, 256, 0, stream>>>(rowloss, out);
}